// Round 4
// baseline (430.263 us; speedup 1.0000x reference)
//
#include <hip/hip_runtime.h>
#include <math.h>

#define BB 8
#define NN 2048
#define FF 64
#define EPSV 1e-5f
#define EMB_SZ (BB * NN * FF)

// workspace float layout
#define WS_SQ      0                      // BB*NN
#define WS_ASUM    (BB * NN)              // BB*FF
#define WS_ASQ     (WS_ASUM + BB * FF)
#define WS_MEAN    (WS_ASQ + BB * FF)
#define WS_RSTD    (WS_MEAN + BB * FF)
#define WS_DEG     (WS_RSTD + BB * FF)    // BB*NN
#define WS_F32_END (WS_DEG + BB * NN)     // 34816 floats
// after WS_F32_END (16B aligned): embBf [BB*NN*FF] bf16, embnT [BB*FF*NN] bf16

typedef __attribute__((ext_vector_type(8))) short bf16x8;
typedef __attribute__((ext_vector_type(4))) float f32x4;
typedef unsigned short ushort_t;

__device__ inline ushort_t f2bf(float x) {
    union { float f; unsigned u; } v; v.f = x;
    return (ushort_t)((v.u + 0x7fffu + ((v.u >> 16) & 1u)) >> 16);
}

// ---------------------------------------------------------------------------
// Kernel 1: per-row squared norm (sq) + per-(b,f) partial sums for mean/var.
// emb_in pre-masked (rows >= nb zero) -> unmasked sums are exact.
// ---------------------------------------------------------------------------
__global__ __launch_bounds__(256) void k_stats(const float* __restrict__ emb,
                                               float* __restrict__ sq,
                                               float* __restrict__ asum,
                                               float* __restrict__ asq) {
    const int b    = blockIdx.y;
    const int lane = threadIdx.x & 63;
    const int grp  = threadIdx.x >> 6;
    const int base_i = blockIdx.x << 6;

    float s = 0.f, q = 0.f;
    for (int it = 0; it < 16; ++it) {
        const int i = base_i + (it << 2) + grp;
        const float x = emb[((size_t)(b * NN + i) << 6) + lane];
        const float x2 = x * x;
        s += x;
        q += x2;
        float r = x2;
        r += __shfl_xor(r, 1);
        r += __shfl_xor(r, 2);
        r += __shfl_xor(r, 4);
        r += __shfl_xor(r, 8);
        r += __shfl_xor(r, 16);
        r += __shfl_xor(r, 32);
        if (lane == 0) sq[b * NN + i] = r;
    }
    __shared__ float redS[4][64];
    __shared__ float redQ[4][64];
    redS[grp][lane] = s;
    redQ[grp][lane] = q;
    __syncthreads();
    if (threadIdx.x < 64) {
        const float ts = redS[0][lane] + redS[1][lane] + redS[2][lane] + redS[3][lane];
        const float tq = redQ[0][lane] + redQ[1][lane] + redQ[2][lane] + redQ[3][lane];
        atomicAdd(&asum[(b << 6) + lane], ts);
        atomicAdd(&asq[(b << 6) + lane], tq);
    }
}

// ---------------------------------------------------------------------------
// Kernel 2: finalize mean / rstd.  1 block, 512 threads (= B*F).
// ---------------------------------------------------------------------------
__global__ void k_finalize(const float* __restrict__ asum, const float* __restrict__ asq,
                           const int* __restrict__ nbp,
                           float* __restrict__ mean, float* __restrict__ rstd) {
    const int t = threadIdx.x;
    const int b = t >> 6;
    const float cnt = fmaxf((float)nbp[b], 1.f);
    const float m = asum[t] / cnt;
    float v = asq[t] / cnt - m * m;
    v = fmaxf(v, 0.f);
    mean[t] = m;
    rstd[t] = rsqrtf(v + EPSV);
}

// ---------------------------------------------------------------------------
// Kernel 3: one-shot precompute of bf16 operands:
//   embBf[b][j][f] = bf16(emb)             (raw, row-major)
//   embnT[b][f][j] = bf16(emb_n) TRANSPOSED (normalized + masked)
// Grid (32, B), 256 thr: 64 rows/block, transpose via LDS.
// ---------------------------------------------------------------------------
__global__ __launch_bounds__(256) void k_prep(const float* __restrict__ emb,
                                              const float* __restrict__ meanp,
                                              const float* __restrict__ rstdp,
                                              const int* __restrict__ nbp,
                                              ushort_t* __restrict__ embBf,
                                              ushort_t* __restrict__ embnT) {
    __shared__ __align__(16) ushort_t T[64][72];
    const int b = blockIdx.y, j0 = blockIdx.x << 6;
    const int nb = nbp[b], bN = b * NN;
    const int t = threadIdx.x;
    const int j = t >> 2, fs = (t & 3) << 4;

    float mn[16], rs[16];
#pragma unroll
    for (int e = 0; e < 16; e += 4) {
        *(float4*)&mn[e] = *(const float4*)(meanp + (b << 6) + fs + e);
        *(float4*)&rs[e] = *(const float4*)(rstdp + (b << 6) + fs + e);
    }
    const float msk = (j0 + j < nb) ? 1.f : 0.f;
    const float* src = emb + ((size_t)(bN + j0 + j) << 6) + fs;
    __align__(16) float x[16];
    *(float4*)(x + 0)  = *(const float4*)(src + 0);
    *(float4*)(x + 4)  = *(const float4*)(src + 4);
    *(float4*)(x + 8)  = *(const float4*)(src + 8);
    *(float4*)(x + 12) = *(const float4*)(src + 12);
    __align__(16) ushort_t raw[16];
#pragma unroll
    for (int e = 0; e < 16; ++e) {
        raw[e] = f2bf(x[e]);
        T[fs + e][j] = f2bf((x[e] - mn[e]) * rs[e] * msk);
    }
    ushort_t* dst = embBf + ((size_t)(bN + j0 + j) << 6) + fs;
    *(bf16x8*)dst       = *(bf16x8*)&raw[0];
    *(bf16x8*)(dst + 8) = *(bf16x8*)&raw[8];
    __syncthreads();
    const int f = t >> 2, js = (t & 3) << 4;
    const bf16x8 v0 = *(bf16x8*)&T[f][js];
    const bf16x8 v1 = *(bf16x8*)&T[f][js + 8];
    ushort_t* dstT = embnT + ((size_t)(b * FF + f) << 11) + j0 + js;
    *(bf16x8*)dstT       = v0;
    *(bf16x8*)(dstT + 8) = v1;
}

// ---------------------------------------------------------------------------
// Kernel 4 (FUSED): per block = (jchunk 512, i0 64 rows, b).  Per 128-j tile:
//   Gram MFMA (embBf) -> d2/exp epilogue -> adj store + deg rowsum
//   -> adj tile to bf16 LDS (XOR-swizzled) -> PV MFMA (adj @ emb_n^T)
//   accumulated in registers; one atomicAdd pass per block into opadj.
// LDS: BgA 16KB (Gram-B [128]x128B, reused as Adjs [64]x256B) + EnT 16KB.
// XOR swizzle: byte ^= (row&7)<<4 on both write & read (G4/T2; 256B-stride
// row-major would otherwise be a 16-way bank conflict on b128 frag reads).
// ---------------------------------------------------------------------------
__global__ __launch_bounds__(256, 4) void k_adj(const ushort_t* __restrict__ embBf,
                                                const ushort_t* __restrict__ embnT,
                                                const float* __restrict__ adj_in,
                                                const float* __restrict__ sq,
                                                const float* __restrict__ sigp,
                                                const float* __restrict__ cw,
                                                const int* __restrict__ nbp,
                                                float* __restrict__ adj_out,
                                                float* __restrict__ deg,
                                                float* __restrict__ opadj) {
    __shared__ __align__(16) ushort_t BgA[8192];
    __shared__ __align__(16) ushort_t EnT[8192];

    const int b = blockIdx.z, i0 = blockIdx.y << 6, jbeg = blockIdx.x << 9;
    const int nb = nbp[b], bN = b * NN;
    const int tid = threadIdx.x, w = tid >> 6, lane = tid & 63;
    const int l15 = lane & 15, lq = lane >> 4;
    const int xk = (l15 & 7) << 4;               // frag-read XOR key
    const bool rowlive = (i0 < nb);
    const int nbr = (nb + 127) & ~127;
    const int jend = min(jbeg + 512, nbr);

    const float inv_sigma = 1.0f / sigp[0];
    const float w0 = cw[0], w1 = cw[1];

    const int ib = i0 + w * 16;
    bf16x8 ah0 = {}, ah1 = {};
    float sqi[4] = {0.f, 0.f, 0.f, 0.f};
    f32x4 accP[4];
#pragma unroll
    for (int c = 0; c < 4; ++c) accP[c] = (f32x4){0.f, 0.f, 0.f, 0.f};
    float rsum[4] = {0.f, 0.f, 0.f, 0.f};

    if (rowlive) {
        const ushort_t* ap = embBf + ((size_t)(bN + ib + l15) << 6) + lq * 8;
        ah0 = *(const bf16x8*)ap;
        ah1 = *(const bf16x8*)(ap + 32);
#pragma unroll
        for (int r = 0; r < 4; ++r) sqi[r] = sq[bN + ib + lq * 4 + r];
    }

    for (int jt = jbeg; jt < jbeg + 512; jt += 128) {
        if (rowlive && jt < jend) {
            // ---- stage Gram-B (embBf rows jt..jt+128) and EnT (emb_n^T)
            {
                const int row = tid >> 1, fs2 = (tid & 1) << 5;
                const ushort_t* src = embBf + ((size_t)(bN + jt + row) << 6) + fs2;
                const int kx = (row & 7) << 4;
#pragma unroll
                for (int e = 0; e < 4; ++e) {
                    const bf16x8 v = *(const bf16x8*)(src + e * 8);
                    *(bf16x8*)((char*)BgA + (((row << 7) + ((fs2 + e * 8) << 1)) ^ kx)) = v;
                }
            }
            {
                const int f = tid >> 2, js = (tid & 3) << 5;
                const ushort_t* src = embnT + ((size_t)(b * FF + f) << 11) + jt + js;
                const int kx = (f & 7) << 4;
#pragma unroll
                for (int e = 0; e < 4; ++e) {
                    const bf16x8 v = *(const bf16x8*)(src + e * 8);
                    *(bf16x8*)((char*)EnT + (((f << 8) + ((js + e * 8) << 1)) ^ kx)) = v;
                }
            }
            __syncthreads();
            // ---- Gram MFMA: acc[c][r] = emb_i . emb_j
            f32x4 acc[8];
#pragma unroll
            for (int c = 0; c < 8; ++c) acc[c] = (f32x4){0.f, 0.f, 0.f, 0.f};
#pragma unroll
            for (int c = 0; c < 8; ++c) {
                const int lin = ((c * 16 + l15) << 7) + lq * 16;
                const bf16x8 b0 = *(const bf16x8*)((char*)BgA + (lin ^ xk));
                const bf16x8 b1 = *(const bf16x8*)((char*)BgA + ((lin + 64) ^ xk));
                acc[c] = __builtin_amdgcn_mfma_f32_16x16x32_bf16(ah0, b0, acc[c], 0, 0, 0);
                acc[c] = __builtin_amdgcn_mfma_f32_16x16x32_bf16(ah1, b1, acc[c], 0, 0, 0);
            }
            // ---- epilogue: d2 -> ker -> adj; store + rowsum; keep in acc
            float sqj[8];
#pragma unroll
            for (int c = 0; c < 8; ++c) sqj[c] = sq[bN + jt + c * 16 + l15];
#pragma unroll
            for (int r = 0; r < 4; ++r) {
                const int gi = ib + lq * 4 + r;
                const float mi = (gi < nb) ? 1.f : 0.f;
                const float* arow = adj_in + ((size_t)(bN + gi) << 11) + jt + l15;
                float* orow = adj_out + ((size_t)(bN + gi) << 11) + jt + l15;
#pragma unroll
                for (int c = 0; c < 8; ++c) {
                    const int gj = jt + c * 16 + l15;
                    float d2 = sqi[r] + sqj[c] - 2.f * acc[c][r];
                    d2 = fmaxf(d2, 0.f);
                    const float ker = __expf(-d2 * inv_sigma);
                    const float mv = (gj < nb) ? mi : 0.f;
                    const float o = (w0 * arow[c * 16] + w1 * ker) * mv;
                    orow[c * 16] = o;
                    acc[c][r] = o;
                    rsum[r] += o;
                }
            }
            __syncthreads();   // Gram-B fully consumed; safe to overwrite as Adjs
            // ---- write adj tile to LDS as bf16 (swizzled)
#pragma unroll
            for (int r = 0; r < 4; ++r) {
                const int iloc = w * 16 + lq * 4 + r;
                const int kx2 = (iloc & 7) << 4;
#pragma unroll
                for (int c = 0; c < 8; ++c) {
                    const int lin = (iloc << 8) + ((c * 16 + l15) << 1);
                    *(ushort_t*)((char*)BgA + (lin ^ kx2)) = f2bf(acc[c][r]);
                }
            }
            __syncthreads();
            // ---- PV MFMA: accP[c] += adj_tile @ emb_n^T  (k = 128 local j)
#pragma unroll
            for (int ks = 0; ks < 4; ++ks) {
                const int lina = ((w * 16 + l15) << 8) + ks * 64 + lq * 16;
                const bf16x8 a = *(const bf16x8*)((char*)BgA + (lina ^ xk));
#pragma unroll
                for (int c = 0; c < 4; ++c) {
                    const int linb = ((c * 16 + l15) << 8) + ks * 64 + lq * 16;
                    const bf16x8 bv = *(const bf16x8*)((char*)EnT + (linb ^ xk));
                    accP[c] = __builtin_amdgcn_mfma_f32_16x16x32_bf16(a, bv, accP[c], 0, 0, 0);
                }
            }
            __syncthreads();   // before next tile's staging overwrites LDS
        } else {
            // dead tile: adj = 0
            const float4 z = make_float4(0.f, 0.f, 0.f, 0.f);
#pragma unroll
            for (int q = 0; q < 8; ++q) {
                const int idx = tid * 8 + q;
                const int row = idx >> 5, c4 = (idx & 31) << 2;
                *(float4*)(adj_out + ((size_t)(bN + i0 + row) << 11) + jt + c4) = z;
            }
        }
    }

    if (rowlive) {
        const int irow = ib + lq * 4;
#pragma unroll
        for (int r = 0; r < 4; ++r) {
            float v = rsum[r];
            v += __shfl_xor(v, 1);
            v += __shfl_xor(v, 2);
            v += __shfl_xor(v, 4);
            v += __shfl_xor(v, 8);
            if (l15 == 0) atomicAdd(&deg[bN + irow + r], v);
        }
#pragma unroll
        for (int c = 0; c < 4; ++c)
#pragma unroll
            for (int r = 0; r < 4; ++r)
                atomicAdd(opadj + ((size_t)(bN + irow + r) << 6) + c * 16 + l15, accP[c][r]);
    }
}

// ---------------------------------------------------------------------------
// Kernel 5: epilogue.  Reads op_adj (emb region of d_out) + deg, builds
// [op_deg | op_adj], conv matmul, nu matmul, relu; overwrites emb_out rows.
// ---------------------------------------------------------------------------
__global__ __launch_bounds__(256) void k_epilogue(const float* __restrict__ emb,
                                                  const float* __restrict__ meanp,
                                                  const float* __restrict__ rstdp,
                                                  const float* __restrict__ degp,
                                                  const int* __restrict__ nbp,
                                                  const float* __restrict__ convW,
                                                  const float* __restrict__ convB,
                                                  const float* __restrict__ nuW,
                                                  const float* __restrict__ nuB,
                                                  float* __restrict__ emb_out) {
    __shared__ __align__(16) float smem[13056];
    float* xs = smem;          // [64][132] [i][op_deg|op_adj]
    float* us = smem + 8704;   // [64][68] emb_upd
    float* es = smem;          // reuse: [64][68] emb_in rows

    const int b   = blockIdx.y;
    const int i0  = blockIdx.x << 6;
    const int tid = threadIdx.x;
    const int tx = tid & 15, ty = tid >> 4;
    const int nb = nbp[b];
    const int bN = b * NN;
    const int sj  = tid >> 2;
    const int scb = (tid & 3) << 4;

    {
        const float4 m4 = *(const float4*)(meanp + (b << 6) + (tx << 2));
        const float4 r4 = *(const float4*)(rstdp + (b << 6) + (tx << 2));
#pragma unroll
        for (int u = 0; u < 4; ++u) {
            const int il = (ty << 2) + u;
            const int gi = i0 + il;
            const float msk = (gi < nb) ? 1.f : 0.f;
            const float dg = degp[bN + gi];
            const float4 v = *(const float4*)(emb + ((size_t)(bN + gi) << 6) + (tx << 2));
            float4 en;
            en.x = (v.x - m4.x) * r4.x * msk;
            en.y = (v.y - m4.y) * r4.y * msk;
            en.z = (v.z - m4.z) * r4.z * msk;
            en.w = (v.w - m4.w) * r4.w * msk;
            float4 od;
            od.x = dg * en.x; od.y = dg * en.y; od.z = dg * en.z; od.w = dg * en.w;
            *(float4*)&xs[il * 132 + (tx << 2)] = od;
            const float4 oa = *(const float4*)(emb_out + ((size_t)(bN + gi) << 6) + (tx << 2));
            *(float4*)&xs[il * 132 + 64 + (tx << 2)] = oa;
        }
    }
    __syncthreads();

    {
        float u4[4][4];
#pragma unroll
        for (int r = 0; r < 4; ++r)
#pragma unroll
            for (int c = 0; c < 4; ++c) u4[r][c] = 0.f;
        for (int fis = 0; fis < 128; fis += 4) {
            const float4 w0v = *(const float4*)(convW + ((fis + 0) << 6) + (tx << 2));
            const float4 w1v = *(const float4*)(convW + ((fis + 1) << 6) + (tx << 2));
            const float4 w2v = *(const float4*)(convW + ((fis + 2) << 6) + (tx << 2));
            const float4 w3v = *(const float4*)(convW + ((fis + 3) << 6) + (tx << 2));
#pragma unroll
            for (int r = 0; r < 4; ++r) {
                const float4 x = *(const float4*)&xs[((ty << 2) + r) * 132 + fis];
                u4[r][0] += x.x * w0v.x + x.y * w1v.x + x.z * w2v.x + x.w * w3v.x;
                u4[r][1] += x.x * w0v.y + x.y * w1v.y + x.z * w2v.y + x.w * w3v.y;
                u4[r][2] += x.x * w0v.z + x.y * w1v.z + x.z * w2v.z + x.w * w3v.z;
                u4[r][3] += x.x * w0v.w + x.y * w1v.w + x.z * w2v.w + x.w * w3v.w;
            }
        }
        const float4 cb4 = *(const float4*)(convB + (tx << 2));
#pragma unroll
        for (int r = 0; r < 4; ++r) {
            float4 o;
            o.x = u4[r][0] + cb4.x; o.y = u4[r][1] + cb4.y;
            o.z = u4[r][2] + cb4.z; o.w = u4[r][3] + cb4.w;
            *(float4*)&us[((ty << 2) + r) * 68 + (tx << 2)] = o;
        }
    }
    __syncthreads();

    {
        const float* pe = emb + ((size_t)(bN + i0 + sj) << 6) + scb;
#pragma unroll
        for (int u = 0; u < 4; ++u)
            *(float4*)&es[sj * 68 + scb + (u << 2)] = *(const float4*)(pe + (u << 2));
    }
    __syncthreads();

    {
        float u4[4][4];
#pragma unroll
        for (int r = 0; r < 4; ++r)
#pragma unroll
            for (int c = 0; c < 4; ++c) u4[r][c] = 0.f;
        for (int fis = 0; fis < 64; fis += 4) {
            const float4 w0v = *(const float4*)(nuW + ((fis + 0) << 6) + (tx << 2));
            const float4 w1v = *(const float4*)(nuW + ((fis + 1) << 6) + (tx << 2));
            const float4 w2v = *(const float4*)(nuW + ((fis + 2) << 6) + (tx << 2));
            const float4 w3v = *(const float4*)(nuW + ((fis + 3) << 6) + (tx << 2));
#pragma unroll
            for (int r = 0; r < 4; ++r) {
                const float4 x = *(const float4*)&es[((ty << 2) + r) * 68 + fis];
                u4[r][0] += x.x * w0v.x + x.y * w1v.x + x.z * w2v.x + x.w * w3v.x;
                u4[r][1] += x.x * w0v.y + x.y * w1v.y + x.z * w2v.y + x.w * w3v.y;
                u4[r][2] += x.x * w0v.z + x.y * w1v.z + x.z * w2v.z + x.w * w3v.z;
                u4[r][3] += x.x * w0v.w + x.y * w1v.w + x.z * w2v.w + x.w * w3v.w;
            }
        }
        for (int fis = 0; fis < 64; fis += 4) {
            const float4 w0v = *(const float4*)(nuW + ((64 + fis + 0) << 6) + (tx << 2));
            const float4 w1v = *(const float4*)(nuW + ((64 + fis + 1) << 6) + (tx << 2));
            const float4 w2v = *(const float4*)(nuW + ((64 + fis + 2) << 6) + (tx << 2));
            const float4 w3v = *(const float4*)(nuW + ((64 + fis + 3) << 6) + (tx << 2));
#pragma unroll
            for (int r = 0; r < 4; ++r) {
                const float4 x = *(const float4*)&us[((ty << 2) + r) * 68 + fis];
                u4[r][0] += x.x * w0v.x + x.y * w1v.x + x.z * w2v.x + x.w * w3v.x;
                u4[r][1] += x.x * w0v.y + x.y * w1v.y + x.z * w2v.y + x.w * w3v.y;
                u4[r][2] += x.x * w0v.z + x.y * w1v.z + x.z * w2v.z + x.w * w3v.z;
                u4[r][3] += x.x * w0v.w + x.y * w1v.w + x.z * w2v.w + x.w * w3v.w;
            }
        }
        const float4 nb4 = *(const float4*)(nuB + (tx << 2));
#pragma unroll
        for (int r = 0; r < 4; ++r) {
            const int gi = i0 + (ty << 2) + r;
            float4 o;
            o.x = fmaxf(u4[r][0] + nb4.x, 0.f);
            o.y = fmaxf(u4[r][1] + nb4.y, 0.f);
            o.z = fmaxf(u4[r][2] + nb4.z, 0.f);
            o.w = fmaxf(u4[r][3] + nb4.w, 0.f);
            *(float4*)(emb_out + ((size_t)(bN + gi) << 6) + (tx << 2)) = o;
        }
    }
}

// ---------------------------------------------------------------------------
extern "C" void kernel_launch(void* const* d_in, const int* in_sizes, int n_in,
                              void* d_out, int out_size, void* d_ws, size_t ws_size,
                              hipStream_t stream) {
    (void)in_sizes; (void)n_in; (void)out_size; (void)ws_size;
    const float* emb_in   = (const float*)d_in[0];
    const float* adj_in   = (const float*)d_in[1];
    const int*   nbp      = (const int*)d_in[3];
    const float* sigp     = (const float*)d_in[4];
    const float* cw       = (const float*)d_in[5];
    const float* convW    = (const float*)d_in[6];
    const float* convB    = (const float*)d_in[7];
    const float* nuW      = (const float*)d_in[8];
    const float* nuB      = (const float*)d_in[9];

    float* emb_out = (float*)d_out;
    float* adj_out = (float*)d_out + EMB_SZ;

    float* ws   = (float*)d_ws;
    float* sq   = ws + WS_SQ;
    float* asum = ws + WS_ASUM;
    float* asq  = ws + WS_ASQ;
    float* mean = ws + WS_MEAN;
    float* rstd = ws + WS_RSTD;
    float* deg  = ws + WS_DEG;
    ushort_t* embBf = (ushort_t*)(ws + WS_F32_END);
    ushort_t* embnT = embBf + (size_t)BB * NN * FF;

    // zero accumulators (ws/d_out are poisoned before every launch)
    hipMemsetAsync(asum, 0, (WS_F32_END - WS_ASUM) * sizeof(float), stream);
    hipMemsetAsync(emb_out, 0, (size_t)EMB_SZ * sizeof(float), stream);

    k_stats<<<dim3(32, BB), 256, 0, stream>>>(emb_in, sq, asum, asq);
    k_finalize<<<1, BB * FF, 0, stream>>>(asum, asq, nbp, mean, rstd);
    k_prep<<<dim3(32, BB), 256, 0, stream>>>(emb_in, mean, rstd, nbp, embBf, embnT);
    k_adj<<<dim3(4, 32, BB), 256, 0, stream>>>(embBf, embnT, adj_in, sq, sigp, cw,
                                               nbp, adj_out, deg, emb_out);
    k_epilogue<<<dim3(32, BB), 256, 0, stream>>>(emb_in, mean, rstd, deg, nbp,
                                                 convW, convB, nuW, nuB, emb_out);
}

// Round 5
// 409.581 us; speedup vs baseline: 1.0505x; 1.0505x over previous
//
#include <hip/hip_runtime.h>
#include <math.h>

#define BB 8
#define NN 2048
#define FF 64
#define EPSV 1e-5f
#define EMB_SZ (BB * NN * FF)

// workspace float layout
#define WS_SQ      0                      // BB*NN
#define WS_ASUM    (BB * NN)              // BB*FF
#define WS_ASQ     (WS_ASUM + BB * FF)
#define WS_MEAN    (WS_ASQ + BB * FF)
#define WS_RSTD    (WS_MEAN + BB * FF)
#define WS_DEG     (WS_RSTD + BB * FF)    // BB*NN
#define WS_F32_END (WS_DEG + BB * NN)     // 34816 floats
// after WS_F32_END (16B aligned): embBf [BB*NN*FF] bf16, embnT [BB*FF*NN] bf16

typedef __attribute__((ext_vector_type(8))) short bf16x8;
typedef __attribute__((ext_vector_type(4))) float f32x4;
typedef unsigned short ushort_t;

__device__ inline ushort_t f2bf(float x) {
    union { float f; unsigned u; } v; v.f = x;
    return (ushort_t)((v.u + 0x7fffu + ((v.u >> 16) & 1u)) >> 16);
}

// ---------------------------------------------------------------------------
// Kernel 1: per-row squared norm (sq) + per-(b,f) partial sums for mean/var.
// emb_in pre-masked (rows >= nb zero) -> unmasked sums are exact.
// ---------------------------------------------------------------------------
__global__ __launch_bounds__(256) void k_stats(const float* __restrict__ emb,
                                               float* __restrict__ sq,
                                               float* __restrict__ asum,
                                               float* __restrict__ asq) {
    const int b    = blockIdx.y;
    const int lane = threadIdx.x & 63;
    const int grp  = threadIdx.x >> 6;
    const int base_i = blockIdx.x << 6;

    float s = 0.f, q = 0.f;
    for (int it = 0; it < 16; ++it) {
        const int i = base_i + (it << 2) + grp;
        const float x = emb[((size_t)(b * NN + i) << 6) + lane];
        const float x2 = x * x;
        s += x;
        q += x2;
        float r = x2;
        r += __shfl_xor(r, 1);
        r += __shfl_xor(r, 2);
        r += __shfl_xor(r, 4);
        r += __shfl_xor(r, 8);
        r += __shfl_xor(r, 16);
        r += __shfl_xor(r, 32);
        if (lane == 0) sq[b * NN + i] = r;
    }
    __shared__ float redS[4][64];
    __shared__ float redQ[4][64];
    redS[grp][lane] = s;
    redQ[grp][lane] = q;
    __syncthreads();
    if (threadIdx.x < 64) {
        const float ts = redS[0][lane] + redS[1][lane] + redS[2][lane] + redS[3][lane];
        const float tq = redQ[0][lane] + redQ[1][lane] + redQ[2][lane] + redQ[3][lane];
        atomicAdd(&asum[(b << 6) + lane], ts);
        atomicAdd(&asq[(b << 6) + lane], tq);
    }
}

// ---------------------------------------------------------------------------
// Kernel 2: finalize mean / rstd.  1 block, 512 threads (= B*F).
// ---------------------------------------------------------------------------
__global__ void k_finalize(const float* __restrict__ asum, const float* __restrict__ asq,
                           const int* __restrict__ nbp,
                           float* __restrict__ mean, float* __restrict__ rstd) {
    const int t = threadIdx.x;
    const int b = t >> 6;
    const float cnt = fmaxf((float)nbp[b], 1.f);
    const float m = asum[t] / cnt;
    float v = asq[t] / cnt - m * m;
    v = fmaxf(v, 0.f);
    mean[t] = m;
    rstd[t] = rsqrtf(v + EPSV);
}

// ---------------------------------------------------------------------------
// Kernel 3: one-shot bf16 operand precompute:
//   embBf[b][j][f] = bf16(emb)              (raw, row-major)
//   embnT[b][f][j] = bf16(emb_n) TRANSPOSED (normalized + masked)
// ---------------------------------------------------------------------------
__global__ __launch_bounds__(256) void k_prep(const float* __restrict__ emb,
                                              const float* __restrict__ meanp,
                                              const float* __restrict__ rstdp,
                                              const int* __restrict__ nbp,
                                              ushort_t* __restrict__ embBf,
                                              ushort_t* __restrict__ embnT) {
    __shared__ __align__(16) ushort_t T[64][72];
    const int b = blockIdx.y, j0 = blockIdx.x << 6;
    const int nb = nbp[b], bN = b * NN;
    const int t = threadIdx.x;
    const int j = t >> 2, fs = (t & 3) << 4;

    float mn[16], rs[16];
#pragma unroll
    for (int e = 0; e < 16; e += 4) {
        *(float4*)&mn[e] = *(const float4*)(meanp + (b << 6) + fs + e);
        *(float4*)&rs[e] = *(const float4*)(rstdp + (b << 6) + fs + e);
    }
    const float msk = (j0 + j < nb) ? 1.f : 0.f;
    const float* src = emb + ((size_t)(bN + j0 + j) << 6) + fs;
    __align__(16) float x[16];
    *(float4*)(x + 0)  = *(const float4*)(src + 0);
    *(float4*)(x + 4)  = *(const float4*)(src + 4);
    *(float4*)(x + 8)  = *(const float4*)(src + 8);
    *(float4*)(x + 12) = *(const float4*)(src + 12);
    __align__(16) ushort_t raw[16];
#pragma unroll
    for (int e = 0; e < 16; ++e) {
        raw[e] = f2bf(x[e]);
        T[fs + e][j] = f2bf((x[e] - mn[e]) * rs[e] * msk);
    }
    ushort_t* dst = embBf + ((size_t)(bN + j0 + j) << 6) + fs;
    *(bf16x8*)dst       = *(bf16x8*)&raw[0];
    *(bf16x8*)(dst + 8) = *(bf16x8*)&raw[8];
    __syncthreads();
    const int f = t >> 2, js = (t & 3) << 4;
    const bf16x8 v0 = *(bf16x8*)&T[f][js];
    const bf16x8 v1 = *(bf16x8*)&T[f][js + 8];
    ushort_t* dstT = embnT + ((size_t)(b * FF + f) << 11) + j0 + js;
    *(bf16x8*)dstT       = v0;
    *(bf16x8*)(dstT + 8) = v1;
}

// ---------------------------------------------------------------------------
// Kernel 4: adj + deg.  NO LDS, NO BARRIERS.  Grid (16j, 32i, B) = 4096
// blocks, 4 waves; wave w owns C rows i0+w*16..+16, cols j0..j0+128.
// All MFMA fragments load directly from embBf (L2-hot bf16); adj_in (the
// only HBM-cold read) is prefetched to registers before the MFMA section.
// C layout: col = l15 (j), row = lq*4+reg (i)  [verified rounds 3-4].
// ---------------------------------------------------------------------------
__global__ __launch_bounds__(256, 4) void k_adj_deg(const ushort_t* __restrict__ embBf,
                                                    const float* __restrict__ adj_in,
                                                    const float* __restrict__ sq,
                                                    const float* __restrict__ sigp,
                                                    const float* __restrict__ cw,
                                                    const int* __restrict__ nbp,
                                                    float* __restrict__ adj_out,
                                                    float* __restrict__ deg) {
    const int b = blockIdx.z, i0 = blockIdx.y << 6, j0 = blockIdx.x << 7;
    const int nb = nbp[b], bN = b * NN;
    const int tid = threadIdx.x, w = tid >> 6, lane = tid & 63;
    const int l15 = lane & 15, lq = lane >> 4;

    if (i0 >= nb || j0 >= nb) {
        const float4 z = make_float4(0.f, 0.f, 0.f, 0.f);
#pragma unroll
        for (int q = 0; q < 8; ++q) {
            const int idx = (tid << 3) + q;     // 0..2047 float4s in 64x128 tile
            const int row = idx >> 5, c4 = (idx & 31) << 2;
            *(float4*)(adj_out + ((size_t)(bN + i0 + row) << 11) + j0 + c4) = z;
        }
        return;
    }

    const int ib = i0 + w * 16;

    // ---- prefetch adj_in (HBM-cold) first so latency drains under compute
    float ain[4][8];
#pragma unroll
    for (int r = 0; r < 4; ++r) {
        const float* arow = adj_in + ((size_t)(bN + ib + lq * 4 + r) << 11) + j0 + l15;
#pragma unroll
        for (int c = 0; c < 8; ++c) ain[r][c] = arow[c << 4];
    }
    float sqi[4], sqj[8];
#pragma unroll
    for (int r = 0; r < 4; ++r) sqi[r] = sq[bN + ib + lq * 4 + r];
#pragma unroll
    for (int c = 0; c < 8; ++c) sqj[c] = sq[bN + j0 + c * 16 + l15];

    // ---- Gram MFMA, fragments straight from global bf16
    const ushort_t* ap = embBf + ((size_t)(bN + ib + l15) << 6) + lq * 8;
    const bf16x8 a0 = *(const bf16x8*)ap;
    const bf16x8 a1 = *(const bf16x8*)(ap + 32);

    f32x4 acc[8];
#pragma unroll
    for (int c = 0; c < 8; ++c) acc[c] = (f32x4){0.f, 0.f, 0.f, 0.f};
#pragma unroll
    for (int c = 0; c < 8; ++c) {
        const ushort_t* bp = embBf + ((size_t)(bN + j0 + c * 16 + l15) << 6) + lq * 8;
        const bf16x8 b0 = *(const bf16x8*)bp;
        const bf16x8 b1 = *(const bf16x8*)(bp + 32);
        acc[c] = __builtin_amdgcn_mfma_f32_16x16x32_bf16(a0, b0, acc[c], 0, 0, 0);
        acc[c] = __builtin_amdgcn_mfma_f32_16x16x32_bf16(a1, b1, acc[c], 0, 0, 0);
    }

    // ---- epilogue: d2 -> ker -> adj store + deg rowsum
    const float inv_sigma = 1.0f / sigp[0];
    const float w0 = cw[0], w1 = cw[1];
#pragma unroll
    for (int r = 0; r < 4; ++r) {
        const int gi = ib + lq * 4 + r;
        const float mi = (gi < nb) ? 1.f : 0.f;
        float* orow = adj_out + ((size_t)(bN + gi) << 11) + j0 + l15;
        float rsum = 0.f;
#pragma unroll
        for (int c = 0; c < 8; ++c) {
            const int gj = j0 + c * 16 + l15;
            float d2 = sqi[r] + sqj[c] - 2.f * acc[c][r];
            d2 = fmaxf(d2, 0.f);
            const float ker = __expf(-d2 * inv_sigma);
            const float mv = (gj < nb) ? mi : 0.f;
            const float o = (w0 * ain[r][c] + w1 * ker) * mv;
            orow[c << 4] = o;
            rsum += o;
        }
        rsum += __shfl_xor(rsum, 1);
        rsum += __shfl_xor(rsum, 2);
        rsum += __shfl_xor(rsum, 4);
        rsum += __shfl_xor(rsum, 8);
        if (l15 == 0) atomicAdd(&deg[bN + gi], rsum);
    }
}

// ---------------------------------------------------------------------------
// Kernel 5: op_adj = adj @ emb_n.  NO LDS, NO BARRIERS.  Grid (32i, 4jc, B),
// 4 waves; wave w owns rows i0+w*16..+16, all 64 f-cols, k = 512-j chunk.
// A-frag: 8 consecutive adj fp32 (L2/L3-fresh) -> bf16 cvt; B-frag: embnT
// [f][j] direct bf16x8.  atomicAdd partials into emb region of d_out.
// ---------------------------------------------------------------------------
__global__ __launch_bounds__(256, 4) void k_opadj(const float* __restrict__ adj,
                                                  const ushort_t* __restrict__ embnT,
                                                  const int* __restrict__ nbp,
                                                  float* __restrict__ opadj) {
    const int b = blockIdx.z, i0 = blockIdx.x << 6, jbeg = blockIdx.y << 9;
    const int nb = nbp[b];
    if (i0 >= nb || jbeg >= nb) return;
    const int bN = b * NN;
    const int jend = min(jbeg + 512, (nb + 31) & ~31);

    const int tid = threadIdx.x, w = tid >> 6, lane = tid & 63;
    const int l15 = lane & 15, lq = lane >> 4;

    const float* arow = adj + ((size_t)(bN + i0 + w * 16 + l15) << 11);
    const ushort_t* bbase = embnT + ((size_t)(b * FF + l15) << 11);

    f32x4 acc[4];
#pragma unroll
    for (int c = 0; c < 4; ++c) acc[c] = (f32x4){0.f, 0.f, 0.f, 0.f};

    for (int jt = jbeg; jt < jend; jt += 32) {
        const float* ap = arow + jt + lq * 8;
        const float4 x0 = *(const float4*)ap;
        const float4 x1 = *(const float4*)(ap + 4);
        __align__(16) ushort_t af[8];
        af[0] = f2bf(x0.x); af[1] = f2bf(x0.y); af[2] = f2bf(x0.z); af[3] = f2bf(x0.w);
        af[4] = f2bf(x1.x); af[5] = f2bf(x1.y); af[6] = f2bf(x1.z); af[7] = f2bf(x1.w);
        const bf16x8 a = *(bf16x8*)af;
#pragma unroll
        for (int c = 0; c < 4; ++c) {
            const bf16x8 bv = *(const bf16x8*)(bbase + ((size_t)(c * 16) << 11) + jt + lq * 8);
            acc[c] = __builtin_amdgcn_mfma_f32_16x16x32_bf16(a, bv, acc[c], 0, 0, 0);
        }
    }

#pragma unroll
    for (int c = 0; c < 4; ++c)
#pragma unroll
        for (int r = 0; r < 4; ++r) {
            const int gi = i0 + w * 16 + lq * 4 + r;
            atomicAdd(opadj + ((size_t)(bN + gi) << 6) + c * 16 + l15, acc[c][r]);
        }
}

// ---------------------------------------------------------------------------
// Kernel 6: epilogue.  Reads op_adj (emb region of d_out) + deg, builds
// [op_deg | op_adj], conv matmul, nu matmul, relu; overwrites emb_out rows.
// ---------------------------------------------------------------------------
__global__ __launch_bounds__(256) void k_epilogue(const float* __restrict__ emb,
                                                  const float* __restrict__ meanp,
                                                  const float* __restrict__ rstdp,
                                                  const float* __restrict__ degp,
                                                  const int* __restrict__ nbp,
                                                  const float* __restrict__ convW,
                                                  const float* __restrict__ convB,
                                                  const float* __restrict__ nuW,
                                                  const float* __restrict__ nuB,
                                                  float* __restrict__ emb_out) {
    __shared__ __align__(16) float smem[13056];
    float* xs = smem;          // [64][132] [i][op_deg|op_adj]
    float* us = smem + 8704;   // [64][68] emb_upd
    float* es = smem;          // reuse: [64][68] emb_in rows

    const int b   = blockIdx.y;
    const int i0  = blockIdx.x << 6;
    const int tid = threadIdx.x;
    const int tx = tid & 15, ty = tid >> 4;
    const int nb = nbp[b];
    const int bN = b * NN;
    const int sj  = tid >> 2;
    const int scb = (tid & 3) << 4;

    {
        const float4 m4 = *(const float4*)(meanp + (b << 6) + (tx << 2));
        const float4 r4 = *(const float4*)(rstdp + (b << 6) + (tx << 2));
#pragma unroll
        for (int u = 0; u < 4; ++u) {
            const int il = (ty << 2) + u;
            const int gi = i0 + il;
            const float msk = (gi < nb) ? 1.f : 0.f;
            const float dg = degp[bN + gi];
            const float4 v = *(const float4*)(emb + ((size_t)(bN + gi) << 6) + (tx << 2));
            float4 en;
            en.x = (v.x - m4.x) * r4.x * msk;
            en.y = (v.y - m4.y) * r4.y * msk;
            en.z = (v.z - m4.z) * r4.z * msk;
            en.w = (v.w - m4.w) * r4.w * msk;
            float4 od;
            od.x = dg * en.x; od.y = dg * en.y; od.z = dg * en.z; od.w = dg * en.w;
            *(float4*)&xs[il * 132 + (tx << 2)] = od;
            const float4 oa = *(const float4*)(emb_out + ((size_t)(bN + gi) << 6) + (tx << 2));
            *(float4*)&xs[il * 132 + 64 + (tx << 2)] = oa;
        }
    }
    __syncthreads();

    {
        float u4[4][4];
#pragma unroll
        for (int r = 0; r < 4; ++r)
#pragma unroll
            for (int c = 0; c < 4; ++c) u4[r][c] = 0.f;
        for (int fis = 0; fis < 128; fis += 4) {
            const float4 w0v = *(const float4*)(convW + ((fis + 0) << 6) + (tx << 2));
            const float4 w1v = *(const float4*)(convW + ((fis + 1) << 6) + (tx << 2));
            const float4 w2v = *(const float4*)(convW + ((fis + 2) << 6) + (tx << 2));
            const float4 w3v = *(const float4*)(convW + ((fis + 3) << 6) + (tx << 2));
#pragma unroll
            for (int r = 0; r < 4; ++r) {
                const float4 x = *(const float4*)&xs[((ty << 2) + r) * 132 + fis];
                u4[r][0] += x.x * w0v.x + x.y * w1v.x + x.z * w2v.x + x.w * w3v.x;
                u4[r][1] += x.x * w0v.y + x.y * w1v.y + x.z * w2v.y + x.w * w3v.y;
                u4[r][2] += x.x * w0v.z + x.y * w1v.z + x.z * w2v.z + x.w * w3v.z;
                u4[r][3] += x.x * w0v.w + x.y * w1v.w + x.z * w2v.w + x.w * w3v.w;
            }
        }
        const float4 cb4 = *(const float4*)(convB + (tx << 2));
#pragma unroll
        for (int r = 0; r < 4; ++r) {
            float4 o;
            o.x = u4[r][0] + cb4.x; o.y = u4[r][1] + cb4.y;
            o.z = u4[r][2] + cb4.z; o.w = u4[r][3] + cb4.w;
            *(float4*)&us[((ty << 2) + r) * 68 + (tx << 2)] = o;
        }
    }
    __syncthreads();

    {
        const float* pe = emb + ((size_t)(bN + i0 + sj) << 6) + scb;
#pragma unroll
        for (int u = 0; u < 4; ++u)
            *(float4*)&es[sj * 68 + scb + (u << 2)] = *(const float4*)(pe + (u << 2));
    }
    __syncthreads();

    {
        float u4[4][4];
#pragma unroll
        for (int r = 0; r < 4; ++r)
#pragma unroll
            for (int c = 0; c < 4; ++c) u4[r][c] = 0.f;
        for (int fis = 0; fis < 64; fis += 4) {
            const float4 w0v = *(const float4*)(nuW + ((fis + 0) << 6) + (tx << 2));
            const float4 w1v = *(const float4*)(nuW + ((fis + 1) << 6) + (tx << 2));
            const float4 w2v = *(const float4*)(nuW + ((fis + 2) << 6) + (tx << 2));
            const float4 w3v = *(const float4*)(nuW + ((fis + 3) << 6) + (tx << 2));
#pragma unroll
            for (int r = 0; r < 4; ++r) {
                const float4 x = *(const float4*)&es[((ty << 2) + r) * 68 + fis];
                u4[r][0] += x.x * w0v.x + x.y * w1v.x + x.z * w2v.x + x.w * w3v.x;
                u4[r][1] += x.x * w0v.y + x.y * w1v.y + x.z * w2v.y + x.w * w3v.y;
                u4[r][2] += x.x * w0v.z + x.y * w1v.z + x.z * w2v.z + x.w * w3v.z;
                u4[r][3] += x.x * w0v.w + x.y * w1v.w + x.z * w2v.w + x.w * w3v.w;
            }
        }
        for (int fis = 0; fis < 64; fis += 4) {
            const float4 w0v = *(const float4*)(nuW + ((64 + fis + 0) << 6) + (tx << 2));
            const float4 w1v = *(const float4*)(nuW + ((64 + fis + 1) << 6) + (tx << 2));
            const float4 w2v = *(const float4*)(nuW + ((64 + fis + 2) << 6) + (tx << 2));
            const float4 w3v = *(const float4*)(nuW + ((64 + fis + 3) << 6) + (tx << 2));
#pragma unroll
            for (int r = 0; r < 4; ++r) {
                const float4 x = *(const float4*)&us[((ty << 2) + r) * 68 + fis];
                u4[r][0] += x.x * w0v.x + x.y * w1v.x + x.z * w2v.x + x.w * w3v.x;
                u4[r][1] += x.x * w0v.y + x.y * w1v.y + x.z * w2v.y + x.w * w3v.y;
                u4[r][2] += x.x * w0v.z + x.y * w1v.z + x.z * w2v.z + x.w * w3v.z;
                u4[r][3] += x.x * w0v.w + x.y * w1v.w + x.z * w2v.w + x.w * w3v.w;
            }
        }
        const float4 nb4 = *(const float4*)(nuB + (tx << 2));
#pragma unroll
        for (int r = 0; r < 4; ++r) {
            const int gi = i0 + (ty << 2) + r;
            float4 o;
            o.x = fmaxf(u4[r][0] + nb4.x, 0.f);
            o.y = fmaxf(u4[r][1] + nb4.y, 0.f);
            o.z = fmaxf(u4[r][2] + nb4.z, 0.f);
            o.w = fmaxf(u4[r][3] + nb4.w, 0.f);
            *(float4*)(emb_out + ((size_t)(bN + gi) << 6) + (tx << 2)) = o;
        }
    }
}

// ---------------------------------------------------------------------------
extern "C" void kernel_launch(void* const* d_in, const int* in_sizes, int n_in,
                              void* d_out, int out_size, void* d_ws, size_t ws_size,
                              hipStream_t stream) {
    (void)in_sizes; (void)n_in; (void)out_size; (void)ws_size;
    const float* emb_in   = (const float*)d_in[0];
    const float* adj_in   = (const float*)d_in[1];
    const int*   nbp      = (const int*)d_in[3];
    const float* sigp     = (const float*)d_in[4];
    const float* cw       = (const float*)d_in[5];
    const float* convW    = (const float*)d_in[6];
    const float* convB    = (const float*)d_in[7];
    const float* nuW      = (const float*)d_in[8];
    const float* nuB      = (const float*)d_in[9];

    float* emb_out = (float*)d_out;
    float* adj_out = (float*)d_out + EMB_SZ;

    float* ws   = (float*)d_ws;
    float* sq   = ws + WS_SQ;
    float* asum = ws + WS_ASUM;
    float* asq  = ws + WS_ASQ;
    float* mean = ws + WS_MEAN;
    float* rstd = ws + WS_RSTD;
    float* deg  = ws + WS_DEG;
    ushort_t* embBf = (ushort_t*)(ws + WS_F32_END);
    ushort_t* embnT = embBf + (size_t)BB * NN * FF;

    // zero accumulators (ws/d_out are poisoned before every launch)
    hipMemsetAsync(asum, 0, (WS_F32_END - WS_ASUM) * sizeof(float), stream);
    hipMemsetAsync(emb_out, 0, (size_t)EMB_SZ * sizeof(float), stream);

    k_stats<<<dim3(32, BB), 256, 0, stream>>>(emb_in, sq, asum, asq);
    k_finalize<<<1, BB * FF, 0, stream>>>(asum, asq, nbp, mean, rstd);
    k_prep<<<dim3(32, BB), 256, 0, stream>>>(emb_in, mean, rstd, nbp, embBf, embnT);
    k_adj_deg<<<dim3(NN / 128, NN / 64, BB), 256, 0, stream>>>(embBf, adj_in, sq, sigp,
                                                               cw, nbp, adj_out, deg);
    k_opadj<<<dim3(NN / 64, 4, BB), 256, 0, stream>>>(adj_out, embnT, nbp, emb_out);
    k_epilogue<<<dim3(32, BB), 256, 0, stream>>>(emb_in, mean, rstd, deg, nbp,
                                                 convW, convB, nuW, nuB, emb_out);
}